// Round 2
// baseline (266.631 us; speedup 1.0000x reference)
//
#include <hip/hip_runtime.h>
#include <math.h>

#define HH 128
#define WW 128

typedef float f32x4 __attribute__((ext_vector_type(4)));

// One block per batch element. 4 waves/block; each wave owns a contiguous
// 16 KiB span of the image (32 rows). Per lane: x is FIXED across all 16
// iterations (4 consecutive pixels), y advances by 2 per iteration.
// out[b,y,x] = exp2( P'*dx^2 + Q'*dx*dy + R'*dy^2 + log2(norm) )
// Stores are NONTEMPORAL: output is write-once, never re-read -> bypass L2
// allocation (the suspected 2.2x-off-roofline store-path limiter).
__global__ __launch_bounds__(256) void MomentsToImage_kernel(
    const float* __restrict__ moments, float* __restrict__ out) {
    const int b = blockIdx.x;
    const float* m = moments + (size_t)b * 6;

    const float sx = (float)(WW - 1);   // 127
    const float sy = (float)(HH - 1);   // 127

    float m0 = m[0], m1 = m[1], m2 = m[2], m3 = m[3], m4 = m[4], m5 = m[5];

    // --- preamble: identical math to the passing kernel ---
    float mux = tanhf(m0) * (sx * 0.5f) + (sx * 0.5f);
    float muy = tanhf(m1) * (sy * 0.5f) + (sy * 0.5f);

    float t0 = fminf(fmaxf(tanhf(m2), 0.03f),   1.0f);
    float t1 = fminf(fmaxf(tanhf(m3), -0.999f), 0.999f);
    float t2 = fminf(fmaxf(tanhf(m4), 0.03f),   1.0f);

    float a  = t0 * (3.0f * sx);
    float bb = t1 * sqrtf(t0 * t2 * (9.0f * sx * sy));
    float c  = t2 * (3.0f * sy);

    float det = a * c - bb * bb;
    float it  = 10.0f / (1.0f + __expf(-m5));          // 10 * sigmoid(m5)
    float norm = it / (6.28318530717958647692f * sqrtf(det));

    float inv_det = 1.0f / det;
    const float L2E = 1.4426950408889634f;             // log2(e)
    float P = (-0.5f * c * inv_det) * L2E;   // coeff of dx^2   (exp2 domain)
    float Q = ( bb * inv_det)       * L2E;   // coeff of dx*dy
    float R = (-0.5f * a * inv_det) * L2E;   // coeff of dy^2
    float n2 = __builtin_amdgcn_logf(norm);  // log2(norm), norm > 0 always

    const int lane = threadIdx.x & 63;
    const int wid  = threadIdx.x >> 6;       // wave id 0..3

    // x for this lane: 4*(lane&31), constant across iterations.
    float d0 = (float)((lane & 31) << 2) - mux;
    float d1 = d0 + 1.0f;
    float d2 = d0 + 2.0f;
    float d3 = d0 + 3.0f;

    // Hoisted per-pixel-column constants (norm folded into A_k).
    float A0 = P * d0 * d0 + n2, B0 = Q * d0;
    float A1 = P * d1 * d1 + n2, B1 = Q * d1;
    float A2 = P * d2 * d2 + n2, B2 = Q * d2;
    float A3 = P * d3 * d3 + n2, B3 = Q * d3;

    // y for this lane at iteration 0: wid*32 + (lane>>5); +2 per iteration.
    float dy = (float)((wid << 5) + (lane >> 5)) - muy;

    // Wave-linear float4 stream: wave `wid` writes [wid*16KiB, +16KiB).
    f32x4* out4 = (f32x4*)(out + (size_t)b * (HH * WW)) + (wid << 10) + lane;

    #pragma unroll
    for (int i = 0; i < 16; ++i) {
        float dy2 = dy * dy;
        float rb  = R * dy2;
        f32x4 o;
        o.x = __builtin_amdgcn_exp2f(fmaf(B0, dy, A0) + rb);
        o.y = __builtin_amdgcn_exp2f(fmaf(B1, dy, A1) + rb);
        o.z = __builtin_amdgcn_exp2f(fmaf(B2, dy, A2) + rb);
        o.w = __builtin_amdgcn_exp2f(fmaf(B3, dy, A3) + rb);
        __builtin_nontemporal_store(o, &out4[i * 64]);
        dy += 2.0f;
    }
}

extern "C" void kernel_launch(void* const* d_in, const int* in_sizes, int n_in,
                              void* d_out, int out_size, void* d_ws, size_t ws_size,
                              hipStream_t stream) {
    const float* moments = (const float*)d_in[0];
    float* out = (float*)d_out;
    int B = in_sizes[0] / 6;             // 4096
    MomentsToImage_kernel<<<dim3(B), dim3(256), 0, stream>>>(moments, out);
}

// Round 3
// 251.341 us; speedup vs baseline: 1.0608x; 1.0608x over previous
//
#include <hip/hip_runtime.h>
#include <math.h>

#define HH 128
#define WW 128
#define IMGS 8   // images per block; 4096/8 = 512 persistent blocks (2 per CU)

typedef float f32x4 __attribute__((ext_vector_type(4)));

// Fill-mimicking dispatch shape: 512 long-lived blocks, each writing ONE
// contiguous 512 KB stream (8 adjacent images). 4 waves/block; per image,
// each wave owns a contiguous 16 KiB span (32 rows). Per lane: x is FIXED
// (4 consecutive pixels), y advances by 2 per iteration.
// out[b,y,x] = exp2( P'*dx^2 + Q'*dx*dy + R'*dy^2 + log2(norm) ),
// P',Q',R' pre-scaled by log2(e). Next image's moments are prefetched into
// registers so the serial preamble hides under the previous image's stores.
__global__ __launch_bounds__(256) void MomentsToImage_kernel(
    const float* __restrict__ moments, float* __restrict__ out) {
    const int b0 = blockIdx.x * IMGS;

    const float sx = (float)(WW - 1);   // 127
    const float sy = (float)(HH - 1);   // 127

    const int lane = threadIdx.x & 63;
    const int wid  = threadIdx.x >> 6;       // wave id 0..3

    // x for this lane: 4*(lane&31), constant across everything.
    const float x0  = (float)((lane & 31) << 2);
    // y origin for this lane: wid*32 + (lane>>5); +2 per inner iteration.
    const float yy0 = (float)((wid << 5) + (lane >> 5));

    // Current image's moments (registers).
    const float* mc = moments + (size_t)b0 * 6;
    float m0 = mc[0], m1 = mc[1], m2 = mc[2], m3 = mc[3], m4 = mc[4], m5 = mc[5];

    #pragma unroll 1
    for (int k = 0; k < IMGS; ++k) {
        const int b = b0 + k;

        // Prefetch next image's moments (no deps -> scheduler issues early,
        // latency hides under this image's preamble + store loop).
        float n0 = 0.f, n1 = 0.f, n2 = 0.f, n3 = 0.f, n4 = 0.f, n5 = 0.f;
        if (k + 1 < IMGS) {
            const float* mn = moments + (size_t)(b + 1) * 6;
            n0 = mn[0]; n1 = mn[1]; n2 = mn[2];
            n3 = mn[3]; n4 = mn[4]; n5 = mn[5];
        }

        // --- preamble: identical math to the passing R1 kernel ---
        float mux = tanhf(m0) * (sx * 0.5f) + (sx * 0.5f);
        float muy = tanhf(m1) * (sy * 0.5f) + (sy * 0.5f);

        float t0 = fminf(fmaxf(tanhf(m2), 0.03f),   1.0f);
        float t1 = fminf(fmaxf(tanhf(m3), -0.999f), 0.999f);
        float t2 = fminf(fmaxf(tanhf(m4), 0.03f),   1.0f);

        float a  = t0 * (3.0f * sx);
        float bb = t1 * sqrtf(t0 * t2 * (9.0f * sx * sy));
        float c  = t2 * (3.0f * sy);

        float det = a * c - bb * bb;
        float it  = 10.0f / (1.0f + __expf(-m5));          // 10 * sigmoid(m5)
        float norm = it / (6.28318530717958647692f * sqrtf(det));

        float inv_det = 1.0f / det;
        const float L2E = 1.4426950408889634f;             // log2(e)
        float P = (-0.5f * c * inv_det) * L2E;   // coeff of dx^2 (exp2 domain)
        float Q = ( bb * inv_det)       * L2E;   // coeff of dx*dy
        float R = (-0.5f * a * inv_det) * L2E;   // coeff of dy^2
        float n2l = __builtin_amdgcn_logf(norm); // log2(norm), norm > 0 always

        float d0 = x0 - mux;
        float d1 = d0 + 1.0f;
        float d2 = d0 + 2.0f;
        float d3 = d0 + 3.0f;

        // Hoisted per-pixel-column constants (norm folded into A_k).
        float A0 = P * d0 * d0 + n2l, B0 = Q * d0;
        float A1 = P * d1 * d1 + n2l, B1 = Q * d1;
        float A2 = P * d2 * d2 + n2l, B2 = Q * d2;
        float A3 = P * d3 * d3 + n2l, B3 = Q * d3;

        float dy = yy0 - muy;

        // Wave-linear float4 stream: wave `wid` writes [wid*16KiB, +16KiB).
        f32x4* out4 = (f32x4*)(out + (size_t)b * (HH * WW)) + (wid << 10) + lane;

        #pragma unroll
        for (int i = 0; i < 16; ++i) {
            float dy2 = dy * dy;
            float rb  = R * dy2;
            f32x4 o;
            o.x = __builtin_amdgcn_exp2f(fmaf(B0, dy, A0) + rb);
            o.y = __builtin_amdgcn_exp2f(fmaf(B1, dy, A1) + rb);
            o.z = __builtin_amdgcn_exp2f(fmaf(B2, dy, A2) + rb);
            o.w = __builtin_amdgcn_exp2f(fmaf(B3, dy, A3) + rb);
            out4[i * 64] = o;
            dy += 2.0f;
        }

        m0 = n0; m1 = n1; m2 = n2; m3 = n3; m4 = n4; m5 = n5;
    }
}

extern "C" void kernel_launch(void* const* d_in, const int* in_sizes, int n_in,
                              void* d_out, int out_size, void* d_ws, size_t ws_size,
                              hipStream_t stream) {
    const float* moments = (const float*)d_in[0];
    float* out = (float*)d_out;
    int B = in_sizes[0] / 6;             // 4096
    MomentsToImage_kernel<<<dim3(B / IMGS), dim3(256), 0, stream>>>(moments, out);
}